// Round 4
// baseline (425.991 us; speedup 1.0000x reference)
//
#include <hip/hip_runtime.h>
#include <cstdint>
#include <cstddef>

#define NC 100  // classes per row

// ---------------- Batcher odd-even mergesort network (compile-time) ----------
struct CP { unsigned char i, j; };

constexpr int net_count() {
  int cnt = 0;
  for (int p = 1; p < NC; p *= 2)
    for (int k = p; k >= 1; k /= 2)
      for (int j = k % p; j + k < NC; j += 2 * k) {
        int lim = (k - 1) < (NC - j - k - 1) ? (k - 1) : (NC - j - k - 1);
        for (int i = 0; i <= lim; ++i)
          if ((i + j) / (2 * p) == (i + j + k) / (2 * p)) ++cnt;
      }
  return cnt;
}
constexpr int NCMP = net_count();

struct Net { CP c[NCMP]; };

constexpr Net make_net() {
  Net n{};
  int cnt = 0;
  for (int p = 1; p < NC; p *= 2)
    for (int k = p; k >= 1; k /= 2)
      for (int j = k % p; j + k < NC; j += 2 * k) {
        int lim = (k - 1) < (NC - j - k - 1) ? (k - 1) : (NC - j - k - 1);
        for (int i = 0; i <= lim; ++i)
          if ((i + j) / (2 * p) == (i + j + k) / (2 * p)) {
            n.c[cnt].i = (unsigned char)(i + j);
            n.c[cnt].j = (unsigned char)(i + j + k);
            ++cnt;
          }
      }
  return n;
}
__device__ constexpr Net NET = make_net();

// ---------------- async global->LDS (16B per lane) ---------------------------
__device__ __forceinline__ void gload_lds16(const void* g, void* l) {
  __builtin_amdgcn_global_load_lds(
      (const __attribute__((address_space(1))) void*)g,
      (__attribute__((address_space(3))) void*)l, 16, 0, 0);
}

// ---------------- main kernel: one row per lane, one wave per block ----------
__global__ __launch_bounds__(64, 2)
void pskd_row_kernel(const float* __restrict__ logits,
                     const float* __restrict__ targets,
                     double* __restrict__ partial) {
  // 25.6 KB: holds t linear (rows of 100 floats), later reused for o linear.
  __shared__ __align__(16) float buf[6400];
  const int lane = threadIdx.x;
  const size_t base = (size_t)blockIdx.x * 64 * NC;
  const float* tsrc = targets + base;
  const float* osrc = logits + base;

  // ---- stage t linearly via async DMA (25.6 KB in flight, zero VALU) ----
  {
    const char* g = (const char*)tsrc + lane * 16;
    char* l = (char*)buf;
    #pragma unroll
    for (int it = 0; it < 25; ++it)
      gload_lds16(g + it * 1024, l + it * 1024);
  }
  asm volatile("s_waitcnt vmcnt(0)" ::: "memory");

  // ---- build 32-bit keys from LDS: descending target, class idx in low 7 bits
  // row stride 400 B = 25 (odd) 16B-slots -> ds_read_b128 conflict-free.
  unsigned a[NC];
  {
    const int rb = lane * NC;
    #pragma unroll
    for (int j = 0; j < 25; ++j) {
      float4 v = *reinterpret_cast<const float4*>(&buf[rb + 4 * j]);
      unsigned m0 = __float_as_uint(v.x), m1 = __float_as_uint(v.y);
      unsigned m2 = __float_as_uint(v.z), m3 = __float_as_uint(v.w);
      a[4 * j + 0] = (~m0 & 0xFFFFFF80u) | (unsigned)(4 * j + 0);
      a[4 * j + 1] = (~m1 & 0xFFFFFF80u) | (unsigned)(4 * j + 1);
      a[4 * j + 2] = (~m2 & 0xFFFFFF80u) | (unsigned)(4 * j + 2);
      a[4 * j + 3] = (~m3 & 0xFFFFFF80u) | (unsigned)(4 * j + 3);
    }
  }
  // key reads must have returned before the o-DMA overwrites buf
  asm volatile("s_waitcnt lgkmcnt(0)" ::: "memory");

  // ---- issue async o staging (linear), hidden under the sorting network ----
  {
    const char* g = (const char*)osrc + lane * 16;
    char* l = (char*)buf;
    #pragma unroll
    for (int it = 0; it < 25; ++it)
      gload_lds16(g + it * 1024, l + it * 1024);
  }

  // ---- register sorting network (ascending key == descending target, stable)
  #pragma unroll
  for (int s = 0; s < NCMP; ++s) {
    const int x = NET.c[s].i;
    const int y = NET.c[s].j;
    unsigned ax = a[x], ay = a[y];
    unsigned mn = ax < ay ? ax : ay;
    unsigned mx = ax < ay ? ay : ax;
    a[x] = mn;
    a[y] = mx;
  }

  asm volatile("s_waitcnt vmcnt(0)" ::: "memory");

  // ---- epilogue: CE + 19 overlapping width-10 windows, base-2 domain ----
  const float L2E = 1.44269504088896340736f;
  const int rb = lane * NC;

  float M = 0.f, S = 0.f;          // global lse accumulators (o' = o*log2e)
  float dot = 0.f, subacc = 0.f;
  float pmo = 0.f, pse = 0.f, pst = 0.f, pdt = 0.f, pref = 0.f;

  #pragma unroll
  for (int c = 0; c < 20; ++c) {
    float tv[5], ov[5];
    #pragma unroll
    for (int q = 0; q < 5; ++q) {
      unsigned k = a[5 * c + q];
      int idx = (int)(k & 127u);
      tv[q] = __uint_as_float(~k & 0xFFFFFF80u) * L2E;  // recovered sorted t'
      ov[q] = buf[rb + idx] * L2E;                      // gathered sorted o'
      dot += tv[q] * ov[q];
    }
    // chunk-of-5 logit stats
    float mo = fmaxf(fmaxf(fmaxf(ov[0], ov[1]), fmaxf(ov[2], ov[3])), ov[4]);
    float se = __builtin_amdgcn_exp2f(ov[0] - mo) + __builtin_amdgcn_exp2f(ov[1] - mo)
             + __builtin_amdgcn_exp2f(ov[2] - mo) + __builtin_amdgcn_exp2f(ov[3] - mo)
             + __builtin_amdgcn_exp2f(ov[4] - mo);
    // chunk-of-5 target stats (t sorted descending -> tv[0] is chunk max)
    float ref = tv[0];
    float e1 = __builtin_amdgcn_exp2f(tv[1] - ref);
    float e2 = __builtin_amdgcn_exp2f(tv[2] - ref);
    float e3 = __builtin_amdgcn_exp2f(tv[3] - ref);
    float e4 = __builtin_amdgcn_exp2f(tv[4] - ref);
    float st = 1.f + e1 + e2 + e3 + e4;
    float dt = ov[0] + e1 * ov[1] + e2 * ov[2] + e3 * ov[3] + e4 * ov[4];

    if (c == 0) {
      M = mo; S = se;
    } else {
      // fold chunk into global lse
      float Mn = fmaxf(M, mo);
      S = S * __builtin_amdgcn_exp2f(M - Mn) + se * __builtin_amdgcn_exp2f(mo - Mn);
      M = Mn;
      // window (c-1, c): start = 5*(c-1), width 10
      float Mw = fmaxf(pmo, mo);
      float Sw = pse * __builtin_amdgcn_exp2f(pmo - Mw)
               + se  * __builtin_amdgcn_exp2f(mo - Mw);
      float lse2 = __builtin_amdgcn_logf(Sw) + Mw;      // v_log_f32 = log2
      float gsc  = __builtin_amdgcn_exp2f(ref - pref);  // rescale to window max
      float stw  = pst + st * gsc;
      float dtw  = pdt + dt * gsc;
      float r    = __builtin_amdgcn_rcpf(stw);
      r = fmaf(fmaf(-stw, r, 1.f), r, r);               // Newton: <1 ulp divide
      subacc += lse2 - dtw * r;
    }
    pmo = mo; pse = se; pst = st; pdt = dt; pref = ref;
  }

  const float LN2 = 0.69314718055994530942f;
  float lse2G = __builtin_amdgcn_logf(S) + M;
  // row = CE + 0.5*sub ; CE = ln2*lse2G - ln2^2*dot' ; sub = ln2*subacc
  float row = LN2 * lse2G - (LN2 * LN2) * dot + 0.5f * LN2 * subacc;

  // deterministic block partial in f64
  double d = (double)row;
  #pragma unroll
  for (int off = 32; off >= 1; off >>= 1)
    d += __shfl_xor(d, off);
  if (lane == 0) partial[blockIdx.x] = d;
}

// ---------------- final reduction --------------------------------------------
__global__ void pskd_reduce_kernel(const double* __restrict__ partial, int n,
                                   float* __restrict__ out, int rows) {
  __shared__ double sm[4];
  double acc = 0.0;
  for (int i = threadIdx.x; i < n; i += 256) acc += partial[i];
  #pragma unroll
  for (int off = 32; off >= 1; off >>= 1) acc += __shfl_xor(acc, off);
  if ((threadIdx.x & 63) == 0) sm[threadIdx.x >> 6] = acc;
  __syncthreads();
  if (threadIdx.x == 0) {
    double tot = sm[0] + sm[1] + sm[2] + sm[3];
    out[0] = (float)(tot / (double)rows);
  }
}

extern "C" void kernel_launch(void* const* d_in, const int* in_sizes, int n_in,
                              void* d_out, int out_size, void* d_ws, size_t ws_size,
                              hipStream_t stream) {
  const float* logits  = (const float*)d_in[0];   // 'output'
  const float* targets = (const float*)d_in[1];   // 'targets'
  float* out = (float*)d_out;
  double* partial = (double*)d_ws;

  const int rows    = in_sizes[0] / NC;   // 524288
  const int nblocks = rows / 64;          // 8192

  pskd_row_kernel<<<nblocks, 64, 0, stream>>>(logits, targets, partial);
  pskd_reduce_kernel<<<1, 256, 0, stream>>>(partial, nblocks, out, rows);
}

// Round 5
// 414.897 us; speedup vs baseline: 1.0267x; 1.0267x over previous
//
#include <hip/hip_runtime.h>
#include <cstdint>
#include <cstddef>

#define NC 100  // classes per row

// ---------------- Batcher odd-even mergesort network (compile-time) ----------
struct CP { unsigned char i, j; };

constexpr int net_count() {
  int cnt = 0;
  for (int p = 1; p < NC; p *= 2)
    for (int k = p; k >= 1; k /= 2)
      for (int j = k % p; j + k < NC; j += 2 * k) {
        int lim = (k - 1) < (NC - j - k - 1) ? (k - 1) : (NC - j - k - 1);
        for (int i = 0; i <= lim; ++i)
          if ((i + j) / (2 * p) == (i + j + k) / (2 * p)) ++cnt;
      }
  return cnt;
}
constexpr int NCMP = net_count();

struct Net { CP c[NCMP]; };

constexpr Net make_net() {
  Net n{};
  int cnt = 0;
  for (int p = 1; p < NC; p *= 2)
    for (int k = p; k >= 1; k /= 2)
      for (int j = k % p; j + k < NC; j += 2 * k) {
        int lim = (k - 1) < (NC - j - k - 1) ? (k - 1) : (NC - j - k - 1);
        for (int i = 0; i <= lim; ++i)
          if ((i + j) / (2 * p) == (i + j + k) / (2 * p)) {
            n.c[cnt].i = (unsigned char)(i + j);
            n.c[cnt].j = (unsigned char)(i + j + k);
            ++cnt;
          }
      }
  return n;
}
__device__ constexpr Net NET = make_net();

// ---------------- async global->LDS (16B per lane) ---------------------------
__device__ __forceinline__ void gload_lds16(const void* g, void* l) {
  __builtin_amdgcn_global_load_lds(
      (const __attribute__((address_space(1))) void*)g,
      (__attribute__((address_space(3))) void*)l, 16, 0, 0);
}

// ---------------- main kernel: one row per lane, one wave per block ----------
// LDS (25.6KB -> 6 blocks/CU) binds occupancy, so a generous VGPR budget is
// free: launch_bounds(64,1) lets the allocator keep all 100 sort keys in
// arch VGPRs (round-4 bench: VGPR_Count=88 < 100 live keys -> AGPR/scratch
// ping-pong, 2.3x VALU inflation).
__global__ __launch_bounds__(64, 1)
void pskd_row_kernel(const float* __restrict__ logits,
                     const float* __restrict__ targets,
                     double* __restrict__ partial) {
  // 25.6 KB: o rows, linear (row stride 100 floats), filled by async DMA.
  __shared__ __align__(16) float obuf[6400];
  const int lane = threadIdx.x;
  const size_t base = (size_t)blockIdx.x * 64 * NC;
  const float* tsrc = targets + base;
  const float* osrc = logits + base;

  // ---- 1. t: per-lane direct global float4 reads (row stride 400B, 16B aligned;
  //         wave span 25.6KB is L1-resident after first touch of each line)
  float4 tv[25];
  {
    const float4* trow = reinterpret_cast<const float4*>(tsrc + lane * NC);
    #pragma unroll
    for (int j = 0; j < 25; ++j) tv[j] = trow[j];
  }

  // ---- 2. issue async o->LDS DMA now; its latency hides under the sort ----
  {
    const char* g = (const char*)osrc + lane * 16;
    char* l = (char*)obuf;
    #pragma unroll
    for (int it = 0; it < 25; ++it)
      gload_lds16(g + it * 1024, l + it * 1024);
  }

  // ---- 3. keys: descending target order, class idx in low 7 bits ----
  unsigned a[NC];
  #pragma unroll
  for (int j = 0; j < 25; ++j) {
    const float* f = reinterpret_cast<const float*>(&tv[j]);
    #pragma unroll
    for (int k = 0; k < 4; ++k) {
      unsigned m = __float_as_uint(f[k]);
      a[4 * j + k] = (~m & 0xFFFFFF80u) | (unsigned)(4 * j + k);
    }
  }

  // ---- 4. register sorting network (ascending key == descending target) ----
  #pragma unroll
  for (int s = 0; s < NCMP; ++s) {
    const int x = NET.c[s].i;
    const int y = NET.c[s].j;
    unsigned ax = a[x], ay = a[y];
    unsigned mn = ax < ay ? ax : ay;
    unsigned mx = ax < ay ? ay : ax;
    a[x] = mn;
    a[y] = mx;
  }

  // ---- 5. single drain: o DMA certainly complete (sort ~4300cy >> latency) ----
  asm volatile("s_waitcnt vmcnt(0)" ::: "memory");

  // ---- 6. epilogue: CE + 19 overlapping width-10 windows, base-2 domain ----
  const float L2E = 1.44269504088896340736f;
  const int rb = lane * NC;

  float M = 0.f, S = 0.f;          // global lse accumulators (o' = o*log2e)
  float dot = 0.f, subacc = 0.f;
  float pmo = 0.f, pse = 0.f, pst = 0.f, pdt = 0.f, pref = 0.f;

  #pragma unroll
  for (int c = 0; c < 20; ++c) {
    float tvv[5], ov[5];
    #pragma unroll
    for (int q = 0; q < 5; ++q) {
      unsigned k = a[5 * c + q];
      int idx = (int)(k & 127u);
      tvv[q] = __uint_as_float(~k & 0xFFFFFF80u) * L2E;  // recovered sorted t'
      ov[q] = obuf[rb + idx] * L2E;                      // gathered sorted o'
      dot += tvv[q] * ov[q];
    }
    // chunk-of-5 logit stats
    float mo = fmaxf(fmaxf(fmaxf(ov[0], ov[1]), fmaxf(ov[2], ov[3])), ov[4]);
    float se = __builtin_amdgcn_exp2f(ov[0] - mo) + __builtin_amdgcn_exp2f(ov[1] - mo)
             + __builtin_amdgcn_exp2f(ov[2] - mo) + __builtin_amdgcn_exp2f(ov[3] - mo)
             + __builtin_amdgcn_exp2f(ov[4] - mo);
    // chunk-of-5 target stats (t sorted descending -> tvv[0] is chunk max)
    float ref = tvv[0];
    float e1 = __builtin_amdgcn_exp2f(tvv[1] - ref);
    float e2 = __builtin_amdgcn_exp2f(tvv[2] - ref);
    float e3 = __builtin_amdgcn_exp2f(tvv[3] - ref);
    float e4 = __builtin_amdgcn_exp2f(tvv[4] - ref);
    float st = 1.f + e1 + e2 + e3 + e4;
    float dt = ov[0] + e1 * ov[1] + e2 * ov[2] + e3 * ov[3] + e4 * ov[4];

    if (c == 0) {
      M = mo; S = se;
    } else {
      // fold chunk into global lse
      float Mn = fmaxf(M, mo);
      S = S * __builtin_amdgcn_exp2f(M - Mn) + se * __builtin_amdgcn_exp2f(mo - Mn);
      M = Mn;
      // window (c-1, c): start = 5*(c-1), width 10
      float Mw = fmaxf(pmo, mo);
      float Sw = pse * __builtin_amdgcn_exp2f(pmo - Mw)
               + se  * __builtin_amdgcn_exp2f(mo - Mw);
      float lse2 = __builtin_amdgcn_logf(Sw) + Mw;      // v_log_f32 = log2
      float gsc  = __builtin_amdgcn_exp2f(ref - pref);  // rescale to window max
      float stw  = pst + st * gsc;
      float dtw  = pdt + dt * gsc;
      float r    = __builtin_amdgcn_rcpf(stw);
      r = fmaf(fmaf(-stw, r, 1.f), r, r);               // Newton: <1 ulp divide
      subacc += lse2 - dtw * r;
    }
    pmo = mo; pse = se; pst = st; pdt = dt; pref = ref;
  }

  const float LN2 = 0.69314718055994530942f;
  float lse2G = __builtin_amdgcn_logf(S) + M;
  // row = CE + 0.5*sub ; CE = ln2*lse2G - ln2^2*dot' ; sub = ln2*subacc
  float row = LN2 * lse2G - (LN2 * LN2) * dot + 0.5f * LN2 * subacc;

  // deterministic block partial in f64
  double d = (double)row;
  #pragma unroll
  for (int off = 32; off >= 1; off >>= 1)
    d += __shfl_xor(d, off);
  if (lane == 0) partial[blockIdx.x] = d;
}

// ---------------- final reduction: 1024 threads, 8 independent loads each ----
__global__ __launch_bounds__(1024)
void pskd_reduce_kernel(const double* __restrict__ partial,
                        float* __restrict__ out, int rows) {
  __shared__ double sm[16];
  const int t = threadIdx.x;
  double s = 0.0;
  #pragma unroll
  for (int k = 0; k < 8; ++k) s += partial[t + k * 1024];   // 8192 partials
  #pragma unroll
  for (int off = 32; off >= 1; off >>= 1) s += __shfl_xor(s, off);
  if ((t & 63) == 0) sm[t >> 6] = s;
  __syncthreads();
  if (t == 0) {
    double tot = 0.0;
    #pragma unroll
    for (int w = 0; w < 16; ++w) tot += sm[w];
    out[0] = (float)(tot / (double)rows);
  }
}

extern "C" void kernel_launch(void* const* d_in, const int* in_sizes, int n_in,
                              void* d_out, int out_size, void* d_ws, size_t ws_size,
                              hipStream_t stream) {
  const float* logits  = (const float*)d_in[0];   // 'output'
  const float* targets = (const float*)d_in[1];   // 'targets'
  float* out = (float*)d_out;
  double* partial = (double*)d_ws;

  const int rows    = in_sizes[0] / NC;   // 524288
  const int nblocks = rows / 64;          // 8192

  pskd_row_kernel<<<nblocks, 64, 0, stream>>>(logits, targets, partial);
  pskd_reduce_kernel<<<1, 1024, 0, stream>>>(partial, out, rows);
}